// Round 6
// baseline (14177.731 us; speedup 1.0000x reference)
//
#include <hip/hip_runtime.h>

namespace {
constexpr int E_ = 512;
constexpr int H_ = 512;
constexpr int O_ = 32;
constexpr int B_ = 64;
constexpr int T_ = 512;
constexpr int RING = 8;
// ws layout (floats)
constexpr size_t H0_OFF   = 0;                         // RING*B*H = 262144
constexpr size_t H1_OFF   = (size_t)RING * B_ * H_;    // 262144
constexpr size_t HF_OFF   = 2 * H1_OFF;                // 524288
constexpr size_t FLAG_OFF = HF_OFF + (size_t)B_ * H_;  // 557056
constexpr size_t FLAG_UINTS = 2048;                    // 2 layers*4 g*4 we*64
constexpr size_t WS_REQUIRED = (FLAG_OFF + FLAG_UINTS) * 4;
}

typedef float f32x4 __attribute__((ext_vector_type(4)));

// ---- coherent LLC primitives. ALL asm loads are SELF-CONTAINED: the
// s_waitcnt lives in the same asm block as the loads, so outputs are valid
// the moment the compiler may spill/copy them (round-3 bug). Immediate
// offsets are 13-bit SIGNED (max 4095): one base pointer per 4KB window. ----
__device__ __forceinline__ void ring_load8(const float* p, f32x4 H[8]) {
    const float* p2 = p + 1024;   // +4096 B
    asm volatile(
        "global_load_dwordx4 %0, %8, off sc0 sc1\n\t"
        "global_load_dwordx4 %1, %8, off offset:1024 sc0 sc1\n\t"
        "global_load_dwordx4 %2, %8, off offset:2048 sc0 sc1\n\t"
        "global_load_dwordx4 %3, %8, off offset:3072 sc0 sc1\n\t"
        "global_load_dwordx4 %4, %9, off sc0 sc1\n\t"
        "global_load_dwordx4 %5, %9, off offset:1024 sc0 sc1\n\t"
        "global_load_dwordx4 %6, %9, off offset:2048 sc0 sc1\n\t"
        "global_load_dwordx4 %7, %9, off offset:3072 sc0 sc1\n\t"
        "s_waitcnt vmcnt(0)"
        : "=&v"(H[0]), "=&v"(H[1]), "=&v"(H[2]), "=&v"(H[3]),
          "=&v"(H[4]), "=&v"(H[5]), "=&v"(H[6]), "=&v"(H[7])
        : "v"(p), "v"(p2) : "memory");
}

__device__ __forceinline__ void ring_load16(const float* p0, const float* p1,
                                            f32x4 A[8], f32x4 Bv[8]) {
    const float* p0b = p0 + 1024;
    const float* p1b = p1 + 1024;
    asm volatile(
        "global_load_dwordx4 %0, %16, off sc0 sc1\n\t"
        "global_load_dwordx4 %1, %16, off offset:1024 sc0 sc1\n\t"
        "global_load_dwordx4 %2, %16, off offset:2048 sc0 sc1\n\t"
        "global_load_dwordx4 %3, %16, off offset:3072 sc0 sc1\n\t"
        "global_load_dwordx4 %4, %17, off sc0 sc1\n\t"
        "global_load_dwordx4 %5, %17, off offset:1024 sc0 sc1\n\t"
        "global_load_dwordx4 %6, %17, off offset:2048 sc0 sc1\n\t"
        "global_load_dwordx4 %7, %17, off offset:3072 sc0 sc1\n\t"
        "global_load_dwordx4 %8, %18, off sc0 sc1\n\t"
        "global_load_dwordx4 %9, %18, off offset:1024 sc0 sc1\n\t"
        "global_load_dwordx4 %10, %18, off offset:2048 sc0 sc1\n\t"
        "global_load_dwordx4 %11, %18, off offset:3072 sc0 sc1\n\t"
        "global_load_dwordx4 %12, %19, off sc0 sc1\n\t"
        "global_load_dwordx4 %13, %19, off offset:1024 sc0 sc1\n\t"
        "global_load_dwordx4 %14, %19, off offset:2048 sc0 sc1\n\t"
        "global_load_dwordx4 %15, %19, off offset:3072 sc0 sc1\n\t"
        "s_waitcnt vmcnt(0)"
        : "=&v"(A[0]), "=&v"(A[1]), "=&v"(A[2]), "=&v"(A[3]),
          "=&v"(A[4]), "=&v"(A[5]), "=&v"(A[6]), "=&v"(A[7]),
          "=&v"(Bv[0]), "=&v"(Bv[1]), "=&v"(Bv[2]), "=&v"(Bv[3]),
          "=&v"(Bv[4]), "=&v"(Bv[5]), "=&v"(Bv[6]), "=&v"(Bv[7])
        : "v"(p0), "v"(p0b), "v"(p1), "v"(p1b) : "memory");
}

__device__ __forceinline__ void vm_drain() {
    asm volatile("s_waitcnt vmcnt(0)" ::: "memory");
}
__device__ __forceinline__ void coh_store(float* p, float v) {
    asm volatile("global_store_dword %0, %1, off sc0 sc1" :: "v"(p), "v"(v) : "memory");
}
__device__ __forceinline__ void flag_store(unsigned* p, unsigned v) {
    asm volatile("global_store_dword %0, %1, off sc0 sc1" :: "v"(p), "v"(v) : "memory");
}
// flag polls: compiler-tracked atomic loads (spill-safe, schedulable; proven r1)
__device__ __forceinline__ unsigned flag_ld(const unsigned* p) {
    return __hip_atomic_load(p, __ATOMIC_RELAXED, __HIP_MEMORY_SCOPE_AGENT);
}

__device__ __forceinline__ float fast_tanh(float x) {
    float e = __builtin_amdgcn_exp2f(x * 2.885390081777927f);
    return 1.0f - 2.0f * __builtin_amdgcn_rcpf(e + 1.0f);
}

// pair-combine butterfly: v[8] partials/lane -> full sum of row (lane&7) on every lane
__device__ __forceinline__ float reduce8(const float v[8], int lane) {
    float a[4];
#pragma unroll
    for (int j = 0; j < 4; ++j) {
        const int sel = lane & 1;
        const float mine = sel ? v[2 * j + 1] : v[2 * j];
        const float send = sel ? v[2 * j] : v[2 * j + 1];
        a[j] = mine + __shfl_xor(send, 1, 64);
    }
    float b[2];
#pragma unroll
    for (int j = 0; j < 2; ++j) {
        const int sel = (lane >> 1) & 1;
        const float mine = sel ? a[2 * j + 1] : a[2 * j];
        const float send = sel ? a[2 * j] : a[2 * j + 1];
        b[j] = mine + __shfl_xor(send, 2, 64);
    }
    const int sel = (lane >> 2) & 1;
    const float mine = sel ? b[1] : b[0];
    const float send = sel ? b[0] : b[1];
    float s = mine + __shfl_xor(send, 4, 64);
    s += __shfl_xor(s, 8, 64);
    s += __shfl_xor(s, 16, 64);
    s += __shfl_xor(s, 32, 64);
    return s;
}

// =====================================================================
// 256 blocks = 2 layers x 4 groups(16 elems) x 32 chunks(16 rows).
// 8 waves/block, fully independent (no LDS/barriers). Wave: 8 rows x 4 elems.
// Lane k-slice: k = chunk*256 + lane*4 + m. Flags per wave (64/producer-set).
// =====================================================================
__global__ __launch_bounds__(512, 1) void rnn_pipe4(
    const int* __restrict__ x, const int* __restrict__ seq_lens,
    const float* __restrict__ emb,
    const float* __restrict__ Whx, const float* __restrict__ Whh,
    const float* __restrict__ b_h,
    float* __restrict__ h0_ring, float* __restrict__ h1_ring,
    float* __restrict__ h1_final, unsigned* __restrict__ flags)
{
    const int bid   = blockIdx.x;
    const int layer = bid >> 7;
    const int g     = (bid >> 5) & 3;
    const int c     = bid & 31;
    const int tid   = threadIdx.x;
    const int wid   = tid >> 6;
    const int lane  = tid & 63;
    const int we    = wid >> 1;
    const int wr    = wid & 1;
    const int rowbase = c * 16 + wr * 8;
    const int eg0   = g * 16 + we * 4;

    // persistent weights: w[r][0..7]=x-part, [8..15]=h-part
    const float* WxL = Whx + (size_t)layer * H_ * E_;
    const float* WhL = Whh + (size_t)layer * H_ * H_;
    float w[8][16];
#pragma unroll
    for (int r = 0; r < 8; ++r) {
        const int row = rowbase + r;
        const f32x4 x0 = *(const f32x4*)(WxL + (size_t)row * E_ + (lane << 2));
        const f32x4 x1 = *(const f32x4*)(WxL + (size_t)row * E_ + 256 + (lane << 2));
        const f32x4 h0 = *(const f32x4*)(WhL + (size_t)row * H_ + (lane << 2));
        const f32x4 h1 = *(const f32x4*)(WhL + (size_t)row * H_ + 256 + (lane << 2));
#pragma unroll
        for (int m = 0; m < 4; ++m) {
            w[r][m] = x0[m]; w[r][4 + m] = x1[m];
            w[r][8 + m] = h0[m]; w[r][12 + m] = h1[m];
        }
    }
    const float bias = b_h[layer * H_ + rowbase + (lane & 7)];

    int sl4[4];
    int Tw = 1;
#pragma unroll
    for (int q = 0; q < 4; ++q) {
        sl4[q] = seq_lens[eg0 + q];
        Tw = sl4[q] > Tw ? sl4[q] : Tw;
    }

    unsigned* const myflag = flags + (((layer * 4 + g) * 4 + we) * 64 + c * 2 + wr);
    const unsigned* const pf0 = flags + ((g * 4 + we) * 64) + lane;          // layer-0 set
    const unsigned* const pf1 = flags + (((4 + g) * 4 + we) * 64) + lane;    // layer-1 set

    long budget = 1l << 26;

    if (layer == 0) {
        // prologue: emb for t=0
        f32x4 X0[4], X1[4];
#pragma unroll
        for (int q = 0; q < 4; ++q) {
            const int tok = x[(size_t)(eg0 + q) * T_];
            X0[q] = *(const f32x4*)(emb + ((size_t)tok << 9) + (lane << 2));
            X1[q] = *(const f32x4*)(emb + ((size_t)tok << 9) + 256 + (lane << 2));
        }
        for (int t = 0; t < Tw; ++t) {
            const int slot  = t & (RING - 1);
            const int pslot = (t - 1) & (RING - 1);
            float vvp[4][8];

            // issue flag polls early; loads are compiler-tracked (schedulable)
            unsigned v0 = 0, v1 = 0;
            if (t > 0) { v0 = flag_ld(pf0); v1 = flag_ld(pf1); }

            // available half: emb part (overlaps flag-poll latency)
#pragma unroll
            for (int q = 0; q < 4; ++q) {
                if (t >= sl4[q]) continue;
#pragma unroll
                for (int r = 0; r < 8; ++r) {
                    float s = w[r][0] * X0[q][0];
                    s = fmaf(w[r][1], X0[q][1], s);
                    s = fmaf(w[r][2], X0[q][2], s);
                    s = fmaf(w[r][3], X0[q][3], s);
                    s = fmaf(w[r][4], X1[q][0], s);
                    s = fmaf(w[r][5], X1[q][1], s);
                    s = fmaf(w[r][6], X1[q][2], s);
                    s = fmaf(w[r][7], X1[q][3], s);
                    vvp[q][r] = s;
                }
            }
            // prefetch emb for t+1 (plain cached loads)
            if (t + 1 < Tw) {
#pragma unroll
                for (int q = 0; q < 4; ++q) {
                    const int tok = x[(size_t)(eg0 + q) * T_ + t + 1];
                    X0[q] = *(const f32x4*)(emb + ((size_t)tok << 9) + (lane << 2));
                    X1[q] = *(const f32x4*)(emb + ((size_t)tok << 9) + 256 + (lane << 2));
                }
            }

            if (t > 0) {
                while (__any(((int)v0 < t) || ((int)v1 < t - 7))) {
                    if (--budget < 0) break;
                    v0 = flag_ld(pf0); v1 = flag_ld(pf1);
                }
                f32x4 H[8];
                ring_load8(h0_ring + (((size_t)pslot << 6) + eg0) * 512 + (lane << 2), H);
#pragma unroll
                for (int q = 0; q < 4; ++q) {
                    if (t >= sl4[q]) continue;
#pragma unroll
                    for (int r = 0; r < 8; ++r) {
                        float s = vvp[q][r];
                        s = fmaf(w[r][8],  H[2 * q][0], s);
                        s = fmaf(w[r][9],  H[2 * q][1], s);
                        s = fmaf(w[r][10], H[2 * q][2], s);
                        s = fmaf(w[r][11], H[2 * q][3], s);
                        s = fmaf(w[r][12], H[2 * q + 1][0], s);
                        s = fmaf(w[r][13], H[2 * q + 1][1], s);
                        s = fmaf(w[r][14], H[2 * q + 1][2], s);
                        s = fmaf(w[r][15], H[2 * q + 1][3], s);
                        vvp[q][r] = s;
                    }
                }
            }

#pragma unroll
            for (int q = 0; q < 4; ++q) {
                if (t >= sl4[q]) continue;
                const float s = reduce8(vvp[q], lane);
                const float hv = fast_tanh(s + bias);
                if (lane < 8)
                    coh_store(h0_ring + (((size_t)slot << 6) + eg0 + q) * 512 + rowbase + lane, hv);
            }
            vm_drain();
            if (lane == 0) flag_store(myflag, (unsigned)(t + 1));
        }
    } else {
        // ---- layer 1 ----
        for (int t = 0; t < Tw; ++t) {
            const int slot  = t & (RING - 1);
            const int pslot = (t - 1) & (RING - 1);
            float vvp[4][8];

            unsigned v0 = flag_ld(pf0), v1 = flag_ld(pf1);
            while (__any(((int)v0 < t + 1) || ((int)v1 < t))) {
                if (--budget < 0) break;
                v0 = flag_ld(pf0); v1 = flag_ld(pf1);
            }

            f32x4 H0[8], H1[8];
            const float* p0 = h0_ring + (((size_t)slot << 6) + eg0) * 512 + (lane << 2);
            if (t > 0) {
                ring_load16(p0, h1_ring + (((size_t)pslot << 6) + eg0) * 512 + (lane << 2), H0, H1);
            } else {
                ring_load8(p0, H0);
            }

#pragma unroll
            for (int q = 0; q < 4; ++q) {
                if (t >= sl4[q]) continue;
#pragma unroll
                for (int r = 0; r < 8; ++r) {
                    float s = w[r][0] * H0[2 * q][0];
                    s = fmaf(w[r][1], H0[2 * q][1], s);
                    s = fmaf(w[r][2], H0[2 * q][2], s);
                    s = fmaf(w[r][3], H0[2 * q][3], s);
                    s = fmaf(w[r][4], H0[2 * q + 1][0], s);
                    s = fmaf(w[r][5], H0[2 * q + 1][1], s);
                    s = fmaf(w[r][6], H0[2 * q + 1][2], s);
                    s = fmaf(w[r][7], H0[2 * q + 1][3], s);
                    vvp[q][r] = s;
                }
            }
            if (t > 0) {
#pragma unroll
                for (int q = 0; q < 4; ++q) {
                    if (t >= sl4[q]) continue;
#pragma unroll
                    for (int r = 0; r < 8; ++r) {
                        float s = vvp[q][r];
                        s = fmaf(w[r][8],  H1[2 * q][0], s);
                        s = fmaf(w[r][9],  H1[2 * q][1], s);
                        s = fmaf(w[r][10], H1[2 * q][2], s);
                        s = fmaf(w[r][11], H1[2 * q][3], s);
                        s = fmaf(w[r][12], H1[2 * q + 1][0], s);
                        s = fmaf(w[r][13], H1[2 * q + 1][1], s);
                        s = fmaf(w[r][14], H1[2 * q + 1][2], s);
                        s = fmaf(w[r][15], H1[2 * q + 1][3], s);
                        vvp[q][r] = s;
                    }
                }
            }

#pragma unroll
            for (int q = 0; q < 4; ++q) {
                if (t >= sl4[q]) continue;
                const float s = reduce8(vvp[q], lane);
                const float hv = fast_tanh(s + bias);
                if (lane < 8) {
                    coh_store(h1_ring + (((size_t)slot << 6) + eg0 + q) * 512 + rowbase + lane, hv);
                    if (t == sl4[q] - 1)
                        h1_final[((size_t)(eg0 + q) << 9) + rowbase + lane] = hv;
                }
            }
            vm_drain();
            if (lane == 0) flag_store(myflag, (unsigned)(t + 1));
        }
    }
}

// ---- final head: y = Wyh[1] @ h1 + b_y[1]; out = Wf @ y + bf ----
__device__ __forceinline__ float dot4(float4 a, float4 b) {
    return fmaf(a.x, b.x, fmaf(a.y, b.y, fmaf(a.z, b.z, a.w * b.w)));
}
__device__ __forceinline__ float wave_reduce(float acc) {
#pragma unroll
    for (int off = 32; off > 0; off >>= 1) acc += __shfl_down(acc, off, 64);
    return acc;
}

__global__ __launch_bounds__(512) void head_kernel(
    const float* __restrict__ h1f, const float* __restrict__ Wyh,
    const float* __restrict__ b_y, const float* __restrict__ Wf,
    const float* __restrict__ bf, float* __restrict__ out)
{
    const int e = blockIdx.x;
    const int tid = threadIdx.x, wid = tid >> 6, lane = tid & 63;
    const int k0 = lane << 3;
    __shared__ float sh[H_];
    __shared__ float sy[H_];
    sh[tid] = h1f[(size_t)e * H_ + tid];
    __syncthreads();
    const float4 hA = *(const float4*)&sh[k0];
    const float4 hB = *(const float4*)&sh[k0 + 4];
    const float* Wy1 = Wyh + H_ * H_;
#pragma unroll 4
    for (int rr = 0; rr < 64; ++rr) {
        const int row = (wid << 6) + rr;
        float acc = wave_reduce(dot4(*(const float4*)&Wy1[(size_t)row * H_ + k0], hA) +
                                dot4(*(const float4*)&Wy1[(size_t)row * H_ + k0 + 4], hB));
        if (lane == 0) sy[row] = acc + b_y[H_ + row];
    }
    __syncthreads();
    const float4 yA = *(const float4*)&sy[k0];
    const float4 yB = *(const float4*)&sy[k0 + 4];
#pragma unroll
    for (int rr = 0; rr < 4; ++rr) {
        const int o = (wid << 2) + rr;
        float acc = wave_reduce(dot4(*(const float4*)&Wf[(size_t)o * H_ + k0], yA) +
                                dot4(*(const float4*)&Wf[(size_t)o * H_ + k0 + 4], yB));
        if (lane == 0) out[(size_t)e * O_ + o] = acc + bf[o];
    }
}

// ---- fallback (round-0, known-passing) ----
__global__ __launch_bounds__(1024, 1) void rnn_fused_fb(
    const int* __restrict__ x, const int* __restrict__ seq_lens,
    const float* __restrict__ emb, const float* __restrict__ Whx,
    const float* __restrict__ Whh, const float* __restrict__ b_h,
    const float* __restrict__ Wyh, const float* __restrict__ b_y,
    const float* __restrict__ Wf, const float* __restrict__ bf,
    float* __restrict__ out)
{
    const int b = blockIdx.x, tid = threadIdx.x;
    const int wave = tid >> 6, lane = tid & 63, k0 = lane << 3;
    __shared__ float s_inp[E_];
    __shared__ float s_h0[2][H_];
    __shared__ float s_h1[2][H_];
    __shared__ float s_y[H_];
    if (tid < H_) { s_h0[0][tid]=0.f; s_h0[1][tid]=0.f; s_h1[0][tid]=0.f; s_h1[1][tid]=0.f; }
    const int Tb = seq_lens[b];
    const float* Whx0 = Whx; const float* Whx1 = Whx + H_*E_;
    const float* Whh0 = Whh; const float* Whh1 = Whh + H_*H_;
    for (int t = 0; t < Tb; ++t) {
        const int cur = t & 1, prv = cur ^ 1;
        if (tid < E_) { const int tok = x[b*T_+t]; s_inp[tid] = emb[(size_t)tok*E_+tid]; }
        __syncthreads();
        const float4 iA = *(const float4*)&s_inp[k0], iB = *(const float4*)&s_inp[k0+4];
        const float4 pA = *(const float4*)&s_h0[prv][k0], pB = *(const float4*)&s_h0[prv][k0+4];
#pragma unroll 4
        for (int r = 0; r < 32; ++r) {
            const int i = (wave<<5)+r;
            float acc = dot4(*(const float4*)&Whx0[i*E_+k0], iA) + dot4(*(const float4*)&Whx0[i*E_+k0+4], iB)
                      + dot4(*(const float4*)&Whh0[i*H_+k0], pA) + dot4(*(const float4*)&Whh0[i*H_+k0+4], pB);
            acc = wave_reduce(acc);
            if (lane == 0) s_h0[cur][i] = tanhf(acc + b_h[i]);
        }
        __syncthreads();
        const float4 cA = *(const float4*)&s_h0[cur][k0], cB = *(const float4*)&s_h0[cur][k0+4];
        const float4 qA = *(const float4*)&s_h1[prv][k0], qB = *(const float4*)&s_h1[prv][k0+4];
#pragma unroll 4
        for (int r = 0; r < 32; ++r) {
            const int i = (wave<<5)+r;
            float acc = dot4(*(const float4*)&Whx1[i*E_+k0], cA) + dot4(*(const float4*)&Whx1[i*E_+k0+4], cB)
                      + dot4(*(const float4*)&Whh1[i*H_+k0], qA) + dot4(*(const float4*)&Whh1[i*H_+k0+4], qB);
            acc = wave_reduce(acc);
            if (lane == 0) s_h1[cur][i] = tanhf(acc + b_h[H_+i]);
        }
        __syncthreads();
    }
    const int lastb = (Tb-1) & 1;
    const float4 hA = *(const float4*)&s_h1[lastb][k0], hB = *(const float4*)&s_h1[lastb][k0+4];
    const float* Wy1 = Wyh + H_*H_;
#pragma unroll 4
    for (int r = 0; r < 32; ++r) {
        const int i = (wave<<5)+r;
        float acc = wave_reduce(dot4(*(const float4*)&Wy1[i*H_+k0], hA) + dot4(*(const float4*)&Wy1[i*H_+k0+4], hB));
        if (lane == 0) s_y[i] = acc + b_y[H_+i];
    }
    __syncthreads();
    const float4 yA = *(const float4*)&s_y[k0], yB = *(const float4*)&s_y[k0+4];
    if (wave < 8) {
#pragma unroll
        for (int r = 0; r < 4; ++r) {
            const int o = (wave<<2)+r;
            float acc = wave_reduce(dot4(*(const float4*)&Wf[o*H_+k0], yA) + dot4(*(const float4*)&Wf[o*H_+k0+4], yB));
            if (lane == 0) out[b*O_+o] = acc + bf[o];
        }
    }
}

extern "C" void kernel_launch(void* const* d_in, const int* in_sizes, int n_in,
                              void* d_out, int out_size, void* d_ws, size_t ws_size,
                              hipStream_t stream) {
    const int*   x    = (const int*)d_in[0];
    const int*   sl   = (const int*)d_in[1];
    const float* emb  = (const float*)d_in[2];
    const float* Whx  = (const float*)d_in[3];
    const float* Whh  = (const float*)d_in[4];
    const float* b_h  = (const float*)d_in[5];
    const float* Wyh  = (const float*)d_in[6];
    const float* b_y  = (const float*)d_in[7];
    const float* Wf   = (const float*)d_in[8];
    const float* bf   = (const float*)d_in[9];
    float* out = (float*)d_out;

    if (ws_size < WS_REQUIRED) {
        rnn_fused_fb<<<B_, 1024, 0, stream>>>(x, sl, emb, Whx, Whh, b_h, Wyh, b_y, Wf, bf, out);
        return;
    }

    float* ws_f = (float*)d_ws;
    float* h0_ring = ws_f + H0_OFF;
    float* h1_ring = ws_f + H1_OFF;
    float* h1f     = ws_f + HF_OFF;
    unsigned* flags = (unsigned*)(ws_f + FLAG_OFF);

    hipMemsetAsync(flags, 0, FLAG_UINTS * sizeof(unsigned), stream);
    rnn_pipe4<<<256, 512, 0, stream>>>(x, sl, emb, Whx, Whh, b_h,
                                       h0_ring, h1_ring, h1f, flags);
    head_kernel<<<B_, 512, 0, stream>>>(h1f, Wyh, b_y, Wf, bf, out);
}

// Round 7
// 13544.206 us; speedup vs baseline: 1.0468x; 1.0468x over previous
//
#include <hip/hip_runtime.h>

namespace {
constexpr int E_ = 512;
constexpr int H_ = 512;
constexpr int O_ = 32;
constexpr int B_ = 64;
constexpr int T_ = 512;
constexpr int RING = 8;
// ws layout (floats)
constexpr size_t H0_OFF   = 0;                         // RING*B*H = 262144
constexpr size_t H1_OFF   = (size_t)RING * B_ * H_;    // 262144
constexpr size_t HF_OFF   = 2 * H1_OFF;                // 524288
constexpr size_t FLAG_OFF = HF_OFF + (size_t)B_ * H_;  // 557056
constexpr size_t FLAG_UINTS = 2048;                    // 2 layers*4 g*4 we*64
constexpr size_t WS_REQUIRED = (FLAG_OFF + FLAG_UINTS) * 4;
}

typedef float f32x4 __attribute__((ext_vector_type(4)));

// ---- coherent LLC primitives. ALL asm loads are SELF-CONTAINED (waitcnt in
// the same asm block) so outputs are valid when regalloc may move them.
// Imm offsets are 13-bit signed: one base VGPR pair per 4KB window. ----
__device__ __forceinline__ void ring_load8(const float* p, f32x4 H[8]) {
    const float* p2 = p + 1024;   // +4096 B
    asm volatile(
        "global_load_dwordx4 %0, %8, off sc0 sc1\n\t"
        "global_load_dwordx4 %1, %8, off offset:1024 sc0 sc1\n\t"
        "global_load_dwordx4 %2, %8, off offset:2048 sc0 sc1\n\t"
        "global_load_dwordx4 %3, %8, off offset:3072 sc0 sc1\n\t"
        "global_load_dwordx4 %4, %9, off sc0 sc1\n\t"
        "global_load_dwordx4 %5, %9, off offset:1024 sc0 sc1\n\t"
        "global_load_dwordx4 %6, %9, off offset:2048 sc0 sc1\n\t"
        "global_load_dwordx4 %7, %9, off offset:3072 sc0 sc1\n\t"
        "s_waitcnt vmcnt(0)"
        : "=&v"(H[0]), "=&v"(H[1]), "=&v"(H[2]), "=&v"(H[3]),
          "=&v"(H[4]), "=&v"(H[5]), "=&v"(H[6]), "=&v"(H[7])
        : "v"(p), "v"(p2) : "memory");
}

__device__ __forceinline__ void ring_load16(const float* p0, const float* p1,
                                            f32x4 A[8], f32x4 Bv[8]) {
    const float* p0b = p0 + 1024;
    const float* p1b = p1 + 1024;
    asm volatile(
        "global_load_dwordx4 %0, %16, off sc0 sc1\n\t"
        "global_load_dwordx4 %1, %16, off offset:1024 sc0 sc1\n\t"
        "global_load_dwordx4 %2, %16, off offset:2048 sc0 sc1\n\t"
        "global_load_dwordx4 %3, %16, off offset:3072 sc0 sc1\n\t"
        "global_load_dwordx4 %4, %17, off sc0 sc1\n\t"
        "global_load_dwordx4 %5, %17, off offset:1024 sc0 sc1\n\t"
        "global_load_dwordx4 %6, %17, off offset:2048 sc0 sc1\n\t"
        "global_load_dwordx4 %7, %17, off offset:3072 sc0 sc1\n\t"
        "global_load_dwordx4 %8, %18, off sc0 sc1\n\t"
        "global_load_dwordx4 %9, %18, off offset:1024 sc0 sc1\n\t"
        "global_load_dwordx4 %10, %18, off offset:2048 sc0 sc1\n\t"
        "global_load_dwordx4 %11, %18, off offset:3072 sc0 sc1\n\t"
        "global_load_dwordx4 %12, %19, off sc0 sc1\n\t"
        "global_load_dwordx4 %13, %19, off offset:1024 sc0 sc1\n\t"
        "global_load_dwordx4 %14, %19, off offset:2048 sc0 sc1\n\t"
        "global_load_dwordx4 %15, %19, off offset:3072 sc0 sc1\n\t"
        "s_waitcnt vmcnt(0)"
        : "=&v"(A[0]), "=&v"(A[1]), "=&v"(A[2]), "=&v"(A[3]),
          "=&v"(A[4]), "=&v"(A[5]), "=&v"(A[6]), "=&v"(A[7]),
          "=&v"(Bv[0]), "=&v"(Bv[1]), "=&v"(Bv[2]), "=&v"(Bv[3]),
          "=&v"(Bv[4]), "=&v"(Bv[5]), "=&v"(Bv[6]), "=&v"(Bv[7])
        : "v"(p0), "v"(p0b), "v"(p1), "v"(p1b) : "memory");
}

__device__ __forceinline__ void vm_drain() {
    asm volatile("s_waitcnt vmcnt(0)" ::: "memory");
}
__device__ __forceinline__ void coh_store(float* p, float v) {
    asm volatile("global_store_dword %0, %1, off sc0 sc1" :: "v"(p), "v"(v) : "memory");
}
__device__ __forceinline__ void flag_store(unsigned* p, unsigned v) {
    asm volatile("global_store_dword %0, %1, off sc0 sc1" :: "v"(p), "v"(v) : "memory");
}
// flag polls: self-contained asm sc0 sc1 (bypass stale L2; round-2-proven).
// __hip_atomic_load(AGENT) was served from stale XCD-L2 -> eviction-paced spins.
__device__ __forceinline__ void flag_poll2(const unsigned* p0, const unsigned* p1,
                                           unsigned& v0, unsigned& v1) {
    asm volatile(
        "global_load_dword %0, %2, off sc0 sc1\n\t"
        "global_load_dword %1, %3, off sc0 sc1\n\t"
        "s_waitcnt vmcnt(0)"
        : "=&v"(v0), "=&v"(v1) : "v"(p0), "v"(p1) : "memory");
}

__device__ __forceinline__ float fast_tanh(float x) {
    float e = __builtin_amdgcn_exp2f(x * 2.885390081777927f);
    return 1.0f - 2.0f * __builtin_amdgcn_rcpf(e + 1.0f);
}

// pair-combine butterfly: v[8] partials/lane -> full sum of row (lane&7) on every lane
__device__ __forceinline__ float reduce8(const float v[8], int lane) {
    float a[4];
#pragma unroll
    for (int j = 0; j < 4; ++j) {
        const int sel = lane & 1;
        const float mine = sel ? v[2 * j + 1] : v[2 * j];
        const float send = sel ? v[2 * j] : v[2 * j + 1];
        a[j] = mine + __shfl_xor(send, 1, 64);
    }
    float b[2];
#pragma unroll
    for (int j = 0; j < 2; ++j) {
        const int sel = (lane >> 1) & 1;
        const float mine = sel ? a[2 * j + 1] : a[2 * j];
        const float send = sel ? a[2 * j] : a[2 * j + 1];
        b[j] = mine + __shfl_xor(send, 2, 64);
    }
    const int sel = (lane >> 2) & 1;
    const float mine = sel ? b[1] : b[0];
    const float send = sel ? b[0] : b[1];
    float s = mine + __shfl_xor(send, 4, 64);
    s += __shfl_xor(s, 8, 64);
    s += __shfl_xor(s, 16, 64);
    s += __shfl_xor(s, 32, 64);
    return s;
}

// =====================================================================
// 256 blocks = 2 layers x 4 groups(16 elems) x 32 chunks(16 rows).
// 8 waves/block, fully independent (no LDS/barriers). Wave: 8 rows x 4 elems.
// Lane k-slice: k = chunk*256 + lane*4 + m. Flags per wave (64/producer-set).
// =====================================================================
__global__ __launch_bounds__(512, 1) void rnn_pipe5(
    const int* __restrict__ x, const int* __restrict__ seq_lens,
    const float* __restrict__ emb,
    const float* __restrict__ Whx, const float* __restrict__ Whh,
    const float* __restrict__ b_h,
    float* __restrict__ h0_ring, float* __restrict__ h1_ring,
    float* __restrict__ h1_final, unsigned* __restrict__ flags)
{
    const int bid   = blockIdx.x;
    const int layer = bid >> 7;
    const int g     = (bid >> 5) & 3;
    const int c     = bid & 31;
    const int tid   = threadIdx.x;
    const int wid   = tid >> 6;
    const int lane  = tid & 63;
    const int we    = wid >> 1;
    const int wr    = wid & 1;
    const int rowbase = c * 16 + wr * 8;
    const int eg0   = g * 16 + we * 4;

    // persistent weights: w[r][0..7]=x-part, [8..15]=h-part
    const float* WxL = Whx + (size_t)layer * H_ * E_;
    const float* WhL = Whh + (size_t)layer * H_ * H_;
    float w[8][16];
#pragma unroll
    for (int r = 0; r < 8; ++r) {
        const int row = rowbase + r;
        const f32x4 x0 = *(const f32x4*)(WxL + (size_t)row * E_ + (lane << 2));
        const f32x4 x1 = *(const f32x4*)(WxL + (size_t)row * E_ + 256 + (lane << 2));
        const f32x4 h0 = *(const f32x4*)(WhL + (size_t)row * H_ + (lane << 2));
        const f32x4 h1 = *(const f32x4*)(WhL + (size_t)row * H_ + 256 + (lane << 2));
#pragma unroll
        for (int m = 0; m < 4; ++m) {
            w[r][m] = x0[m]; w[r][4 + m] = x1[m];
            w[r][8 + m] = h0[m]; w[r][12 + m] = h1[m];
        }
    }
    const float bias = b_h[layer * H_ + rowbase + (lane & 7)];

    int sl4[4];
    int Tw = 1;
#pragma unroll
    for (int q = 0; q < 4; ++q) {
        sl4[q] = seq_lens[eg0 + q];
        Tw = sl4[q] > Tw ? sl4[q] : Tw;
    }

    unsigned* const myflag = flags + (((layer * 4 + g) * 4 + we) * 64 + c * 2 + wr);
    const unsigned* const pf0 = flags + ((g * 4 + we) * 64) + lane;          // layer-0 set
    const unsigned* const pf1 = flags + (((4 + g) * 4 + we) * 64) + lane;    // layer-1 set

    long budget = 1l << 24;

    if (layer == 0) {
        // prologue: emb for t=0
        f32x4 X0[4], X1[4];
#pragma unroll
        for (int q = 0; q < 4; ++q) {
            const int tok = x[(size_t)(eg0 + q) * T_];
            X0[q] = *(const f32x4*)(emb + ((size_t)tok << 9) + (lane << 2));
            X1[q] = *(const f32x4*)(emb + ((size_t)tok << 9) + 256 + (lane << 2));
        }
        for (int t = 0; t < Tw; ++t) {
            const int slot  = t & (RING - 1);
            const int pslot = (t - 1) & (RING - 1);
            float vvp[4][8];

            // available half: emb part
#pragma unroll
            for (int q = 0; q < 4; ++q) {
                if (t >= sl4[q]) continue;
#pragma unroll
                for (int r = 0; r < 8; ++r) {
                    float s = w[r][0] * X0[q][0];
                    s = fmaf(w[r][1], X0[q][1], s);
                    s = fmaf(w[r][2], X0[q][2], s);
                    s = fmaf(w[r][3], X0[q][3], s);
                    s = fmaf(w[r][4], X1[q][0], s);
                    s = fmaf(w[r][5], X1[q][1], s);
                    s = fmaf(w[r][6], X1[q][2], s);
                    s = fmaf(w[r][7], X1[q][3], s);
                    vvp[q][r] = s;
                }
            }
            // prefetch emb for t+1 (plain cached loads)
            if (t + 1 < Tw) {
#pragma unroll
                for (int q = 0; q < 4; ++q) {
                    const int tok = x[(size_t)(eg0 + q) * T_ + t + 1];
                    X0[q] = *(const f32x4*)(emb + ((size_t)tok << 9) + (lane << 2));
                    X1[q] = *(const f32x4*)(emb + ((size_t)tok << 9) + 256 + (lane << 2));
                }
            }

            if (t > 0) {
                for (;;) {
                    unsigned v0, v1;
                    flag_poll2(pf0, pf1, v0, v1);
                    if (!__any(((int)v0 < t) || ((int)v1 < t - 7))) break;
                    if (--budget < 0) break;
                }
                f32x4 H[8];
                ring_load8(h0_ring + (((size_t)pslot << 6) + eg0) * 512 + (lane << 2), H);
#pragma unroll
                for (int q = 0; q < 4; ++q) {
                    if (t >= sl4[q]) continue;
#pragma unroll
                    for (int r = 0; r < 8; ++r) {
                        float s = vvp[q][r];
                        s = fmaf(w[r][8],  H[2 * q][0], s);
                        s = fmaf(w[r][9],  H[2 * q][1], s);
                        s = fmaf(w[r][10], H[2 * q][2], s);
                        s = fmaf(w[r][11], H[2 * q][3], s);
                        s = fmaf(w[r][12], H[2 * q + 1][0], s);
                        s = fmaf(w[r][13], H[2 * q + 1][1], s);
                        s = fmaf(w[r][14], H[2 * q + 1][2], s);
                        s = fmaf(w[r][15], H[2 * q + 1][3], s);
                        vvp[q][r] = s;
                    }
                }
            }

#pragma unroll
            for (int q = 0; q < 4; ++q) {
                if (t >= sl4[q]) continue;
                const float s = reduce8(vvp[q], lane);
                const float hv = fast_tanh(s + bias);
                if (lane < 8)
                    coh_store(h0_ring + (((size_t)slot << 6) + eg0 + q) * 512 + rowbase + lane, hv);
            }
            vm_drain();
            if (lane == 0) flag_store(myflag, (unsigned)(t + 1));
        }
    } else {
        // ---- layer 1 ----
        for (int t = 0; t < Tw; ++t) {
            const int slot  = t & (RING - 1);
            const int pslot = (t - 1) & (RING - 1);
            float vvp[4][8];

            for (;;) {
                unsigned v0, v1;
                flag_poll2(pf0, pf1, v0, v1);
                if (!__any(((int)v0 < t + 1) || ((int)v1 < t))) break;
                if (--budget < 0) break;
            }

            f32x4 H0[8], H1[8];
            const float* p0 = h0_ring + (((size_t)slot << 6) + eg0) * 512 + (lane << 2);
            if (t > 0) {
                ring_load16(p0, h1_ring + (((size_t)pslot << 6) + eg0) * 512 + (lane << 2), H0, H1);
            } else {
                ring_load8(p0, H0);
            }

#pragma unroll
            for (int q = 0; q < 4; ++q) {
                if (t >= sl4[q]) continue;
#pragma unroll
                for (int r = 0; r < 8; ++r) {
                    float s = w[r][0] * H0[2 * q][0];
                    s = fmaf(w[r][1], H0[2 * q][1], s);
                    s = fmaf(w[r][2], H0[2 * q][2], s);
                    s = fmaf(w[r][3], H0[2 * q][3], s);
                    s = fmaf(w[r][4], H0[2 * q + 1][0], s);
                    s = fmaf(w[r][5], H0[2 * q + 1][1], s);
                    s = fmaf(w[r][6], H0[2 * q + 1][2], s);
                    s = fmaf(w[r][7], H0[2 * q + 1][3], s);
                    vvp[q][r] = s;
                }
            }
            if (t > 0) {
#pragma unroll
                for (int q = 0; q < 4; ++q) {
                    if (t >= sl4[q]) continue;
#pragma unroll
                    for (int r = 0; r < 8; ++r) {
                        float s = vvp[q][r];
                        s = fmaf(w[r][8],  H1[2 * q][0], s);
                        s = fmaf(w[r][9],  H1[2 * q][1], s);
                        s = fmaf(w[r][10], H1[2 * q][2], s);
                        s = fmaf(w[r][11], H1[2 * q][3], s);
                        s = fmaf(w[r][12], H1[2 * q + 1][0], s);
                        s = fmaf(w[r][13], H1[2 * q + 1][1], s);
                        s = fmaf(w[r][14], H1[2 * q + 1][2], s);
                        s = fmaf(w[r][15], H1[2 * q + 1][3], s);
                        vvp[q][r] = s;
                    }
                }
            }

#pragma unroll
            for (int q = 0; q < 4; ++q) {
                if (t >= sl4[q]) continue;
                const float s = reduce8(vvp[q], lane);
                const float hv = fast_tanh(s + bias);
                if (lane < 8) {
                    coh_store(h1_ring + (((size_t)slot << 6) + eg0 + q) * 512 + rowbase + lane, hv);
                    if (t == sl4[q] - 1)
                        h1_final[((size_t)(eg0 + q) << 9) + rowbase + lane] = hv;
                }
            }
            vm_drain();
            if (lane == 0) flag_store(myflag, (unsigned)(t + 1));
        }
    }
}

// ---- final head: y = Wyh[1] @ h1 + b_y[1]; out = Wf @ y + bf ----
__device__ __forceinline__ float dot4(float4 a, float4 b) {
    return fmaf(a.x, b.x, fmaf(a.y, b.y, fmaf(a.z, b.z, a.w * b.w)));
}
__device__ __forceinline__ float wave_reduce(float acc) {
#pragma unroll
    for (int off = 32; off > 0; off >>= 1) acc += __shfl_down(acc, off, 64);
    return acc;
}

__global__ __launch_bounds__(512) void head_kernel(
    const float* __restrict__ h1f, const float* __restrict__ Wyh,
    const float* __restrict__ b_y, const float* __restrict__ Wf,
    const float* __restrict__ bf, float* __restrict__ out)
{
    const int e = blockIdx.x;
    const int tid = threadIdx.x, wid = tid >> 6, lane = tid & 63;
    const int k0 = lane << 3;
    __shared__ float sh[H_];
    __shared__ float sy[H_];
    sh[tid] = h1f[(size_t)e * H_ + tid];
    __syncthreads();
    const float4 hA = *(const float4*)&sh[k0];
    const float4 hB = *(const float4*)&sh[k0 + 4];
    const float* Wy1 = Wyh + H_ * H_;
#pragma unroll 4
    for (int rr = 0; rr < 64; ++rr) {
        const int row = (wid << 6) + rr;
        float acc = wave_reduce(dot4(*(const float4*)&Wy1[(size_t)row * H_ + k0], hA) +
                                dot4(*(const float4*)&Wy1[(size_t)row * H_ + k0 + 4], hB));
        if (lane == 0) sy[row] = acc + b_y[H_ + row];
    }
    __syncthreads();
    const float4 yA = *(const float4*)&sy[k0];
    const float4 yB = *(const float4*)&sy[k0 + 4];
#pragma unroll
    for (int rr = 0; rr < 4; ++rr) {
        const int o = (wid << 2) + rr;
        float acc = wave_reduce(dot4(*(const float4*)&Wf[(size_t)o * H_ + k0], yA) +
                                dot4(*(const float4*)&Wf[(size_t)o * H_ + k0 + 4], yB));
        if (lane == 0) out[(size_t)e * O_ + o] = acc + bf[o];
    }
}

// ---- fallback (round-0, known-passing) ----
__global__ __launch_bounds__(1024, 1) void rnn_fused_fb(
    const int* __restrict__ x, const int* __restrict__ seq_lens,
    const float* __restrict__ emb, const float* __restrict__ Whx,
    const float* __restrict__ Whh, const float* __restrict__ b_h,
    const float* __restrict__ Wyh, const float* __restrict__ b_y,
    const float* __restrict__ Wf, const float* __restrict__ bf,
    float* __restrict__ out)
{
    const int b = blockIdx.x, tid = threadIdx.x;
    const int wave = tid >> 6, lane = tid & 63, k0 = lane << 3;
    __shared__ float s_inp[E_];
    __shared__ float s_h0[2][H_];
    __shared__ float s_h1[2][H_];
    __shared__ float s_y[H_];
    if (tid < H_) { s_h0[0][tid]=0.f; s_h0[1][tid]=0.f; s_h1[0][tid]=0.f; s_h1[1][tid]=0.f; }
    const int Tb = seq_lens[b];
    const float* Whx0 = Whx; const float* Whx1 = Whx + H_*E_;
    const float* Whh0 = Whh; const float* Whh1 = Whh + H_*H_;
    for (int t = 0; t < Tb; ++t) {
        const int cur = t & 1, prv = cur ^ 1;
        if (tid < E_) { const int tok = x[b*T_+t]; s_inp[tid] = emb[(size_t)tok*E_+tid]; }
        __syncthreads();
        const float4 iA = *(const float4*)&s_inp[k0], iB = *(const float4*)&s_inp[k0+4];
        const float4 pA = *(const float4*)&s_h0[prv][k0], pB = *(const float4*)&s_h0[prv][k0+4];
#pragma unroll 4
        for (int r = 0; r < 32; ++r) {
            const int i = (wave<<5)+r;
            float acc = dot4(*(const float4*)&Whx0[i*E_+k0], iA) + dot4(*(const float4*)&Whx0[i*E_+k0+4], iB)
                      + dot4(*(const float4*)&Whh0[i*H_+k0], pA) + dot4(*(const float4*)&Whh0[i*H_+k0+4], pB);
            acc = wave_reduce(acc);
            if (lane == 0) s_h0[cur][i] = tanhf(acc + b_h[i]);
        }
        __syncthreads();
        const float4 cA = *(const float4*)&s_h0[cur][k0], cB = *(const float4*)&s_h0[cur][k0+4];
        const float4 qA = *(const float4*)&s_h1[prv][k0], qB = *(const float4*)&s_h1[prv][k0+4];
#pragma unroll 4
        for (int r = 0; r < 32; ++r) {
            const int i = (wave<<5)+r;
            float acc = dot4(*(const float4*)&Whx1[i*E_+k0], cA) + dot4(*(const float4*)&Whx1[i*E_+k0+4], cB)
                      + dot4(*(const float4*)&Whh1[i*H_+k0], qA) + dot4(*(const float4*)&Whh1[i*H_+k0+4], qB);
            acc = wave_reduce(acc);
            if (lane == 0) s_h1[cur][i] = tanhf(acc + b_h[H_+i]);
        }
        __syncthreads();
    }
    const int lastb = (Tb-1) & 1;
    const float4 hA = *(const float4*)&s_h1[lastb][k0], hB = *(const float4*)&s_h1[lastb][k0+4];
    const float* Wy1 = Wyh + H_*H_;
#pragma unroll 4
    for (int r = 0; r < 32; ++r) {
        const int i = (wave<<5)+r;
        float acc = wave_reduce(dot4(*(const float4*)&Wy1[i*H_+k0], hA) + dot4(*(const float4*)&Wy1[i*H_+k0+4], hB));
        if (lane == 0) s_y[i] = acc + b_y[H_+i];
    }
    __syncthreads();
    const float4 yA = *(const float4*)&s_y[k0], yB = *(const float4*)&s_y[k0+4];
    if (wave < 8) {
#pragma unroll
        for (int r = 0; r < 4; ++r) {
            const int o = (wave<<2)+r;
            float acc = wave_reduce(dot4(*(const float4*)&Wf[o*H_+k0], yA) + dot4(*(const float4*)&Wf[o*H_+k0+4], yB));
            if (lane == 0) out[b*O_+o] = acc + bf[o];
        }
    }
}

extern "C" void kernel_launch(void* const* d_in, const int* in_sizes, int n_in,
                              void* d_out, int out_size, void* d_ws, size_t ws_size,
                              hipStream_t stream) {
    const int*   x    = (const int*)d_in[0];
    const int*   sl   = (const int*)d_in[1];
    const float* emb  = (const float*)d_in[2];
    const float* Whx  = (const float*)d_in[3];
    const float* Whh  = (const float*)d_in[4];
    const float* b_h  = (const float*)d_in[5];
    const float* Wyh  = (const float*)d_in[6];
    const float* b_y  = (const float*)d_in[7];
    const float* Wf   = (const float*)d_in[8];
    const float* bf   = (const float*)d_in[9];
    float* out = (float*)d_out;

    if (ws_size < WS_REQUIRED) {
        rnn_fused_fb<<<B_, 1024, 0, stream>>>(x, sl, emb, Whx, Whh, b_h, Wyh, b_y, Wf, bf, out);
        return;
    }

    float* ws_f = (float*)d_ws;
    float* h0_ring = ws_f + H0_OFF;
    float* h1_ring = ws_f + H1_OFF;
    float* h1f     = ws_f + HF_OFF;
    unsigned* flags = (unsigned*)(ws_f + FLAG_OFF);

    hipMemsetAsync(flags, 0, FLAG_UINTS * sizeof(unsigned), stream);
    rnn_pipe5<<<256, 512, 0, stream>>>(x, sl, emb, Whx, Whh, b_h,
                                       h0_ring, h1_ring, h1f, flags);
    head_kernel<<<B_, 512, 0, stream>>>(h1f, Wyh, b_y, Wf, bf, out);
}

// Round 8
// 1991.329 us; speedup vs baseline: 7.1197x; 6.8016x over previous
//
#include <hip/hip_runtime.h>

namespace {
constexpr int E_ = 512;
constexpr int H_ = 512;
constexpr int O_ = 32;
constexpr int B_ = 64;
constexpr int T_ = 512;
constexpr int RING = 8;
constexpr int FPAD = 16;                               // 64B per flag
// ws layout (floats)
constexpr size_t H0_OFF   = 0;                         // RING*B*H = 262144
constexpr size_t H1_OFF   = (size_t)RING * B_ * H_;    // 262144
constexpr size_t HF_OFF   = 2 * H1_OFF;                // 524288
constexpr size_t FLAG_OFF = HF_OFF + (size_t)B_ * H_;  // 557056
constexpr size_t FLAG_UINTS = 2u * 8u * 16u * FPAD;    // 4096
constexpr size_t WS_REQUIRED = (FLAG_OFF + FLAG_UINTS) * 4;  // 2,244,608 B
}

typedef float f32x4 __attribute__((ext_vector_type(4)));

// ---- coherent LLC primitives; all loads SELF-CONTAINED (waitcnt inside) ----
__device__ __forceinline__ void coh_ld8(const float* p, f32x4& a, f32x4& b) {
    asm volatile(
        "global_load_dwordx4 %0, %2, off sc0 sc1\n\t"
        "global_load_dwordx4 %1, %2, off offset:16 sc0 sc1\n\t"
        "s_waitcnt vmcnt(0)"
        : "=&v"(a), "=&v"(b) : "v"(p) : "memory");
}
__device__ __forceinline__ void coh_ld16(const float* p, const float* q,
                                         f32x4& a, f32x4& b, f32x4& c, f32x4& d) {
    asm volatile(
        "global_load_dwordx4 %0, %4, off sc0 sc1\n\t"
        "global_load_dwordx4 %1, %4, off offset:16 sc0 sc1\n\t"
        "global_load_dwordx4 %2, %5, off sc0 sc1\n\t"
        "global_load_dwordx4 %3, %5, off offset:16 sc0 sc1\n\t"
        "s_waitcnt vmcnt(0)"
        : "=&v"(a), "=&v"(b), "=&v"(c), "=&v"(d) : "v"(p), "v"(q) : "memory");
}
__device__ __forceinline__ unsigned flag_poll(const unsigned* p) {
    unsigned v;
    asm volatile("global_load_dword %0, %1, off sc0 sc1\n\ts_waitcnt vmcnt(0)"
                 : "=&v"(v) : "v"(p) : "memory");
    return v;
}
__device__ __forceinline__ void vm_drain() {
    asm volatile("s_waitcnt vmcnt(0)" ::: "memory");
}
__device__ __forceinline__ void coh_store(float* p, float v) {
    asm volatile("global_store_dword %0, %1, off sc0 sc1" :: "v"(p), "v"(v) : "memory");
}
__device__ __forceinline__ void flag_store(unsigned* p, unsigned v) {
    asm volatile("global_store_dword %0, %1, off sc0 sc1" :: "v"(p), "v"(v) : "memory");
}

__device__ __forceinline__ float fast_tanh(float x) {
    float e = __builtin_amdgcn_exp2f(x * 2.885390081777927f);
    return 1.0f - 2.0f * __builtin_amdgcn_rcpf(e + 1.0f);
}

// pair-combine butterfly: v[8] partials/lane -> full sum of row (lane&7) on every lane
__device__ __forceinline__ float reduce8(const float v[8], int lane) {
    float a[4];
#pragma unroll
    for (int j = 0; j < 4; ++j) {
        const int sel = lane & 1;
        const float mine = sel ? v[2 * j + 1] : v[2 * j];
        const float send = sel ? v[2 * j] : v[2 * j + 1];
        a[j] = mine + __shfl_xor(send, 1, 64);
    }
    float b[2];
#pragma unroll
    for (int j = 0; j < 2; ++j) {
        const int sel = (lane >> 1) & 1;
        const float mine = sel ? a[2 * j + 1] : a[2 * j];
        const float send = sel ? a[2 * j] : a[2 * j + 1];
        b[j] = mine + __shfl_xor(send, 2, 64);
    }
    const int sel = (lane >> 2) & 1;
    const float mine = sel ? b[1] : b[0];
    const float send = sel ? b[0] : b[1];
    float s = mine + __shfl_xor(send, 4, 64);
    s += __shfl_xor(s, 8, 64);
    s += __shfl_xor(s, 16, 64);
    s += __shfl_xor(s, 32, 64);
    return s;
}

// =====================================================================
// Round-2 proven topology: 256 blocks = 2 layers x 8 groups(8 elems) x
// 16 chunks(32 rows); 8 waves; wave = 8 rows (wr=wid&3) x 4 elems (we=wid>>2).
// Block-cooperative: single poller wave, LDS broadcast staging, 3 barriers.
// Upgrades vs r2: butterfly reduce + lane-parallel tanh; L0 split-half
// (emb FMAs before poll/stage); no s_sleep; bounds(512,1) -> no spills.
// Lane k-slice: k = ck*256 + lane*4 + m (lane-contiguous 16B, 0 conflicts).
// =====================================================================
__global__ __launch_bounds__(512, 1) void rnn_pipe6(
    const int* __restrict__ x, const int* __restrict__ seq_lens,
    const float* __restrict__ emb,
    const float* __restrict__ Whx, const float* __restrict__ Whh,
    const float* __restrict__ b_h,
    float* __restrict__ h0_ring, float* __restrict__ h1_ring,
    float* __restrict__ h1_final, unsigned* __restrict__ flags)
{
    const int bid   = blockIdx.x;
    const int layer = bid >> 7;
    const int g     = (bid >> 4) & 7;
    const int c     = bid & 15;
    const int tid   = threadIdx.x;
    const int wid   = tid >> 6;
    const int lane  = tid & 63;
    const int we    = wid >> 2;          // elem half (4 elems)
    const int wr    = wid & 3;           // row octet
    const int rowbase = c * 32 + wr * 8;
    const int eg0   = g * 8 + we * 4;

    __shared__ float sx[2][4096];        // x double-buffer (L0)
    __shared__ float sh[4096];           // fresh operand (h0_prev / h0(t))
    __shared__ float sh1[4096];          // L1: h1(t-1)

    // persistent weights: w[r][0..7]=x-part, [8..15]=h-part
    const float* WxL = Whx + (size_t)layer * H_ * E_;
    const float* WhL = Whh + (size_t)layer * H_ * H_;
    float w[8][16];
#pragma unroll
    for (int r = 0; r < 8; ++r) {
        const int row = rowbase + r;
        const f32x4 x0 = *(const f32x4*)(WxL + (size_t)row * E_ + (lane << 2));
        const f32x4 x1 = *(const f32x4*)(WxL + (size_t)row * E_ + 256 + (lane << 2));
        const f32x4 h0 = *(const f32x4*)(WhL + (size_t)row * H_ + (lane << 2));
        const f32x4 h1 = *(const f32x4*)(WhL + (size_t)row * H_ + 256 + (lane << 2));
#pragma unroll
        for (int m = 0; m < 4; ++m) {
            w[r][m] = x0[m]; w[r][4 + m] = x1[m];
            w[r][8 + m] = h0[m]; w[r][12 + m] = h1[m];
        }
    }
    const float bias = b_h[layer * H_ + rowbase + (lane & 7)];

    int sl4[4];
#pragma unroll
    for (int q = 0; q < 4; ++q) sl4[q] = seq_lens[eg0 + q];
    int Tg = 1;
#pragma unroll
    for (int j = 0; j < 8; ++j) {
        const int s = seq_lens[g * 8 + j];
        Tg = s > Tg ? s : Tg;
    }

    // flags: [2][8][16] blocks x FPAD. Poller = wave 0; lanes<16 watch L0 set,
    // lanes 16..31 watch L1 set.
    unsigned* const myflag = flags + ((size_t)((layer * 8 + g) * 16 + c)) * FPAD;
    const unsigned* pollp = flags + ((size_t)((0 * 8 + g) * 16 + (lane & 15))) * FPAD;
    if (lane >= 16 && lane < 32)
        pollp = flags + ((size_t)((8 + g) * 16 + (lane - 16))) * FPAD;

    const int se  = wid;                 // staging: elem = wave id
    const int off = (tid & 63) << 3;     // 8-float slice
    const int seg = g * 8 + se;

    long budget = 1l << 24;

    if (layer == 0) {
        // stage x(0)
        {
            const int tok = x[(size_t)seg * T_];
            const f32x4 e0 = *(const f32x4*)(emb + ((size_t)tok << 9) + off);
            const f32x4 e1 = *(const f32x4*)(emb + ((size_t)tok << 9) + off + 4);
            *(f32x4*)&sx[0][(se << 9) + off] = e0;
            *(f32x4*)&sx[0][(se << 9) + off + 4] = e1;
        }
        __syncthreads();

        for (int t = 0; t < Tg; ++t) {
            const int cur = t & 1, slot = t & 7, pslot = (t - 1) & 7;
            float vvp[4][8];

            // ---- emb-half (available operand) ----
#pragma unroll
            for (int q = 0; q < 4; ++q) {
                if (t >= sl4[q]) continue;
                const int el = (we << 2) + q;
                const f32x4 lx0 = *(const f32x4*)&sx[cur][(el << 9) + (lane << 2)];
                const f32x4 lx1 = *(const f32x4*)&sx[cur][(el << 9) + 256 + (lane << 2)];
#pragma unroll
                for (int r = 0; r < 8; ++r) {
                    float s = w[r][0] * lx0[0];
                    s = fmaf(w[r][1], lx0[1], s);
                    s = fmaf(w[r][2], lx0[2], s);
                    s = fmaf(w[r][3], lx0[3], s);
                    s = fmaf(w[r][4], lx1[0], s);
                    s = fmaf(w[r][5], lx1[1], s);
                    s = fmaf(w[r][6], lx1[2], s);
                    s = fmaf(w[r][7], lx1[3], s);
                    vvp[q][r] = s;
                }
            }

            // ---- poll: cnt0 >= t (h0(t-1) complete), cnt1 >= t-7 (ring bp) ----
            if (wid == 0 && t > 0) {
                const int tgt = (lane < 16) ? t : ((lane < 32) ? t - 7 : 0);
                for (;;) {
                    const unsigned v = flag_poll(pollp);
                    if (!__any((int)v < tgt)) break;
                    if (--budget < 0) break;
                }
            }
            __syncthreads();

            // ---- stage h0(t-1) -> sh ----
            if (t > 0) {
                f32x4 a, b;
                coh_ld8(h0_ring + (((size_t)pslot << 6) + seg) * 512 + off, a, b);
                *(f32x4*)&sh[(se << 9) + off] = a;
                *(f32x4*)&sh[(se << 9) + off + 4] = b;
            } else {
                f32x4 z = 0;
                *(f32x4*)&sh[(se << 9) + off] = z;
                *(f32x4*)&sh[(se << 9) + off + 4] = z;
            }
            // prefetch x(t+1) (plain cached loads; land during compute)
            f32x4 px0, px1;
            const bool havepf = (t + 1 < Tg);
            if (havepf) {
                const int tok = x[(size_t)seg * T_ + t + 1];
                px0 = *(const f32x4*)(emb + ((size_t)tok << 9) + off);
                px1 = *(const f32x4*)(emb + ((size_t)tok << 9) + off + 4);
            }
            __syncthreads();

            // ---- h-half + epilogue ----
#pragma unroll
            for (int q = 0; q < 4; ++q) {
                if (t >= sl4[q]) continue;
                const int el = (we << 2) + q;
                const f32x4 h0a = *(const f32x4*)&sh[(el << 9) + (lane << 2)];
                const f32x4 h0b = *(const f32x4*)&sh[(el << 9) + 256 + (lane << 2)];
#pragma unroll
                for (int r = 0; r < 8; ++r) {
                    float s = vvp[q][r];
                    s = fmaf(w[r][8],  h0a[0], s);
                    s = fmaf(w[r][9],  h0a[1], s);
                    s = fmaf(w[r][10], h0a[2], s);
                    s = fmaf(w[r][11], h0a[3], s);
                    s = fmaf(w[r][12], h0b[0], s);
                    s = fmaf(w[r][13], h0b[1], s);
                    s = fmaf(w[r][14], h0b[2], s);
                    s = fmaf(w[r][15], h0b[3], s);
                    vvp[q][r] = s;
                }
                const float sum = reduce8(vvp[q], lane);
                const float hv = fast_tanh(sum + bias);
                if (lane < 8)
                    coh_store(h0_ring + (((size_t)slot << 6) + eg0 + q) * 512 + rowbase + lane, hv);
            }
            if (havepf) {
                *(f32x4*)&sx[cur ^ 1][(se << 9) + off] = px0;
                *(f32x4*)&sx[cur ^ 1][(se << 9) + off + 4] = px1;
            }
            vm_drain();
            __syncthreads();
            if (tid == 0) flag_store(myflag, (unsigned)(t + 1));
        }
    } else {
        // ---- layer 1 ----
        for (int t = 0; t < Tg; ++t) {
            const int slot = t & 7, pslot = (t - 1) & 7;
            float vvp[4][8];

            // poll: cnt0 >= t+1 (h0(t) ready), cnt1 >= t (h1(t-1) ready)
            if (wid == 0) {
                const int tgt = (lane < 16) ? t + 1 : ((lane < 32) ? t : 0);
                for (;;) {
                    const unsigned v = flag_poll(pollp);
                    if (!__any((int)v < tgt)) break;
                    if (--budget < 0) break;
                }
            }
            __syncthreads();

            // stage h0(t)->sh, h1(t-1)->sh1
            if (t > 0) {
                f32x4 a, b, cc, d;
                coh_ld16(h0_ring + (((size_t)slot << 6) + seg) * 512 + off,
                         h1_ring + (((size_t)pslot << 6) + seg) * 512 + off, a, b, cc, d);
                *(f32x4*)&sh[(se << 9) + off] = a;
                *(f32x4*)&sh[(se << 9) + off + 4] = b;
                *(f32x4*)&sh1[(se << 9) + off] = cc;
                *(f32x4*)&sh1[(se << 9) + off + 4] = d;
            } else {
                f32x4 a, b;
                coh_ld8(h0_ring + (((size_t)slot << 6) + seg) * 512 + off, a, b);
                *(f32x4*)&sh[(se << 9) + off] = a;
                *(f32x4*)&sh[(se << 9) + off + 4] = b;
                f32x4 z = 0;
                *(f32x4*)&sh1[(se << 9) + off] = z;
                *(f32x4*)&sh1[(se << 9) + off + 4] = z;
            }
            __syncthreads();

#pragma unroll
            for (int q = 0; q < 4; ++q) {
                if (t >= sl4[q]) continue;
                const int el = (we << 2) + q;
                const f32x4 xa = *(const f32x4*)&sh[(el << 9) + (lane << 2)];
                const f32x4 xb = *(const f32x4*)&sh[(el << 9) + 256 + (lane << 2)];
                const f32x4 ha = *(const f32x4*)&sh1[(el << 9) + (lane << 2)];
                const f32x4 hb = *(const f32x4*)&sh1[(el << 9) + 256 + (lane << 2)];
#pragma unroll
                for (int r = 0; r < 8; ++r) {
                    float s = w[r][0] * xa[0];
                    s = fmaf(w[r][1], xa[1], s);
                    s = fmaf(w[r][2], xa[2], s);
                    s = fmaf(w[r][3], xa[3], s);
                    s = fmaf(w[r][4], xb[0], s);
                    s = fmaf(w[r][5], xb[1], s);
                    s = fmaf(w[r][6], xb[2], s);
                    s = fmaf(w[r][7], xb[3], s);
                    s = fmaf(w[r][8],  ha[0], s);
                    s = fmaf(w[r][9],  ha[1], s);
                    s = fmaf(w[r][10], ha[2], s);
                    s = fmaf(w[r][11], ha[3], s);
                    s = fmaf(w[r][12], hb[0], s);
                    s = fmaf(w[r][13], hb[1], s);
                    s = fmaf(w[r][14], hb[2], s);
                    s = fmaf(w[r][15], hb[3], s);
                    vvp[q][r] = s;
                }
                const float sum = reduce8(vvp[q], lane);
                const float hv = fast_tanh(sum + bias);
                if (lane < 8) {
                    coh_store(h1_ring + (((size_t)slot << 6) + eg0 + q) * 512 + rowbase + lane, hv);
                    if (t == sl4[q] - 1)
                        h1_final[((size_t)(eg0 + q) << 9) + rowbase + lane] = hv;
                }
            }
            vm_drain();
            __syncthreads();
            if (tid == 0) flag_store(myflag, (unsigned)(t + 1));
        }
    }
}

// ---- final head: y = Wyh[1] @ h1 + b_y[1]; out = Wf @ y + bf ----
__device__ __forceinline__ float dot4(float4 a, float4 b) {
    return fmaf(a.x, b.x, fmaf(a.y, b.y, fmaf(a.z, b.z, a.w * b.w)));
}
__device__ __forceinline__ float wave_reduce(float acc) {
#pragma unroll
    for (int off = 32; off > 0; off >>= 1) acc += __shfl_down(acc, off, 64);
    return acc;
}

__global__ __launch_bounds__(512) void head_kernel(
    const float* __restrict__ h1f, const float* __restrict__ Wyh,
    const float* __restrict__ b_y, const float* __restrict__ Wf,
    const float* __restrict__ bf, float* __restrict__ out)
{
    const int e = blockIdx.x;
    const int tid = threadIdx.x, wid = tid >> 6, lane = tid & 63;
    const int k0 = lane << 3;
    __shared__ float sh[H_];
    __shared__ float sy[H_];
    sh[tid] = h1f[(size_t)e * H_ + tid];
    __syncthreads();
    const float4 hA = *(const float4*)&sh[k0];
    const float4 hB = *(const float4*)&sh[k0 + 4];
    const float* Wy1 = Wyh + H_ * H_;
#pragma unroll 4
    for (int rr = 0; rr < 64; ++rr) {
        const int row = (wid << 6) + rr;
        float acc = wave_reduce(dot4(*(const float4*)&Wy1[(size_t)row * H_ + k0], hA) +
                                dot4(*(const float4*)&Wy1[(size_t)row * H_ + k0 + 4], hB));
        if (lane == 0) sy[row] = acc + b_y[H_ + row];
    }
    __syncthreads();
    const float4 yA = *(const float4*)&sy[k0];
    const float4 yB = *(const float4*)&sy[k0 + 4];
#pragma unroll
    for (int rr = 0; rr < 4; ++rr) {
        const int o = (wid << 2) + rr;
        float acc = wave_reduce(dot4(*(const float4*)&Wf[(size_t)o * H_ + k0], yA) +
                                dot4(*(const float4*)&Wf[(size_t)o * H_ + k0 + 4], yB));
        if (lane == 0) out[(size_t)e * O_ + o] = acc + bf[o];
    }
}

// ---- fallback (round-0, known-passing) ----
__global__ __launch_bounds__(1024, 1) void rnn_fused_fb(
    const int* __restrict__ x, const int* __restrict__ seq_lens,
    const float* __restrict__ emb, const float* __restrict__ Whx,
    const float* __restrict__ Whh, const float* __restrict__ b_h,
    const float* __restrict__ Wyh, const float* __restrict__ b_y,
    const float* __restrict__ Wf, const float* __restrict__ bf,
    float* __restrict__ out)
{
    const int b = blockIdx.x, tid = threadIdx.x;
    const int wave = tid >> 6, lane = tid & 63, k0 = lane << 3;
    __shared__ float s_inp[E_];
    __shared__ float s_h0[2][H_];
    __shared__ float s_h1[2][H_];
    __shared__ float s_y[H_];
    if (tid < H_) { s_h0[0][tid]=0.f; s_h0[1][tid]=0.f; s_h1[0][tid]=0.f; s_h1[1][tid]=0.f; }
    const int Tb = seq_lens[b];
    const float* Whx0 = Whx; const float* Whx1 = Whx + H_*E_;
    const float* Whh0 = Whh; const float* Whh1 = Whh + H_*H_;
    for (int t = 0; t < Tb; ++t) {
        const int cur = t & 1, prv = cur ^ 1;
        if (tid < E_) { const int tok = x[b*T_+t]; s_inp[tid] = emb[(size_t)tok*E_+tid]; }
        __syncthreads();
        const float4 iA = *(const float4*)&s_inp[k0], iB = *(const float4*)&s_inp[k0+4];
        const float4 pA = *(const float4*)&s_h0[prv][k0], pB = *(const float4*)&s_h0[prv][k0+4];
#pragma unroll 4
        for (int r = 0; r < 32; ++r) {
            const int i = (wave<<5)+r;
            float acc = dot4(*(const float4*)&Whx0[i*E_+k0], iA) + dot4(*(const float4*)&Whx0[i*E_+k0+4], iB)
                      + dot4(*(const float4*)&Whh0[i*H_+k0], pA) + dot4(*(const float4*)&Whh0[i*H_+k0+4], pB);
            acc = wave_reduce(acc);
            if (lane == 0) s_h0[cur][i] = tanhf(acc + b_h[i]);
        }
        __syncthreads();
        const float4 cA = *(const float4*)&s_h0[cur][k0], cB = *(const float4*)&s_h0[cur][k0+4];
        const float4 qA = *(const float4*)&s_h1[prv][k0], qB = *(const float4*)&s_h1[prv][k0+4];
#pragma unroll 4
        for (int r = 0; r < 32; ++r) {
            const int i = (wave<<5)+r;
            float acc = dot4(*(const float4*)&Whx1[i*E_+k0], cA) + dot4(*(const float4*)&Whx1[i*E_+k0+4], cB)
                      + dot4(*(const float4*)&Whh1[i*H_+k0], qA) + dot4(*(const float4*)&Whh1[i*H_+k0+4], qB);
            acc = wave_reduce(acc);
            if (lane == 0) s_h1[cur][i] = tanhf(acc + b_h[H_+i]);
        }
        __syncthreads();
    }
    const int lastb = (Tb-1) & 1;
    const float4 hA = *(const float4*)&s_h1[lastb][k0], hB = *(const float4*)&s_h1[lastb][k0+4];
    const float* Wy1 = Wyh + H_*H_;
#pragma unroll 4
    for (int r = 0; r < 32; ++r) {
        const int i = (wave<<5)+r;
        float acc = wave_reduce(dot4(*(const float4*)&Wy1[i*H_+k0], hA) + dot4(*(const float4*)&Wy1[i*H_+k0+4], hB));
        if (lane == 0) s_y[i] = acc + b_y[H_+i];
    }
    __syncthreads();
    const float4 yA = *(const float4*)&s_y[k0], yB = *(const float4*)&s_y[k0+4];
    if (wave < 8) {
#pragma unroll
        for (int r = 0; r < 4; ++r) {
            const int o = (wave<<2)+r;
            float acc = wave_reduce(dot4(*(const float4*)&Wf[o*H_+k0], yA) + dot4(*(const float4*)&Wf[o*H_+k0+4], yB));
            if (lane == 0) out[b*O_+o] = acc + bf[o];
        }
    }
}

extern "C" void kernel_launch(void* const* d_in, const int* in_sizes, int n_in,
                              void* d_out, int out_size, void* d_ws, size_t ws_size,
                              hipStream_t stream) {
    const int*   x    = (const int*)d_in[0];
    const int*   sl   = (const int*)d_in[1];
    const float* emb  = (const float*)d_in[2];
    const float* Whx  = (const float*)d_in[3];
    const float* Whh  = (const float*)d_in[4];
    const float* b_h  = (const float*)d_in[5];
    const float* Wyh  = (const float*)d_in[6];
    const float* b_y  = (const float*)d_in[7];
    const float* Wf   = (const float*)d_in[8];
    const float* bf   = (const float*)d_in[9];
    float* out = (float*)d_out;

    if (ws_size < WS_REQUIRED) {
        rnn_fused_fb<<<B_, 1024, 0, stream>>>(x, sl, emb, Whx, Whh, b_h, Wyh, b_y, Wf, bf, out);
        return;
    }

    float* ws_f = (float*)d_ws;
    float* h0_ring = ws_f + H0_OFF;
    float* h1_ring = ws_f + H1_OFF;
    float* h1f     = ws_f + HF_OFF;
    unsigned* flags = (unsigned*)(ws_f + FLAG_OFF);

    hipMemsetAsync(flags, 0, FLAG_UINTS * sizeof(unsigned), stream);
    rnn_pipe6<<<256, 512, 0, stream>>>(x, sl, emb, Whx, Whh, b_h,
                                       h0_ring, h1_ring, h1f, flags);
    head_kernel<<<B_, 512, 0, stream>>>(h1f, Wyh, b_y, Wf, bf, out);
}